// Round 8
// baseline (685.655 us; speedup 1.0000x reference)
//
#include <hip/hip_runtime.h>

#define N_NODES 100000
#define N_EDGES 320000
#define N_GRAPHS 512

typedef unsigned short bf16_t;
typedef __attribute__((ext_vector_type(8))) short short8;            // 8 bf16 = 4 VGPR
typedef __attribute__((ext_vector_type(8))) unsigned short ushort8_t;
typedef __attribute__((ext_vector_type(4))) float f32x4;

__device__ inline float bf2f(unsigned short b) {
    unsigned int u = ((unsigned int)b) << 16;
    float f; __builtin_memcpy(&f, &u, 4); return f;
}
__device__ inline unsigned short f2bf(float f) {
    unsigned int u; __builtin_memcpy(&u, &f, 4);
    u = (u + 0x7FFFu + ((u >> 16) & 1u)) >> 16;   // RNE
    return (unsigned short)u;
}

// ---------------- sentinel ----------------
__global__ void sentinel_kernel(float* out, int n) {
    int i = blockIdx.x * blockDim.x + threadIdx.x;
    if (i < n) out[i] = 12345.0f;
}

// ---------------- zero degi + flag ----------------
__global__ void zero_misc_kernel(int* __restrict__ degi, int* __restrict__ flag, int n) {
    int i = blockIdx.x * blockDim.x + threadIdx.x;
    if (i < n) degi[i] = 0;
    if (i == 0) *flag = 0;
}

// ---------------- int64-vs-int32 index detection ----------------
__global__ void detect_kernel(const int* __restrict__ ei32, int* __restrict__ flag, int nOdd) {
    int i = blockIdx.x * blockDim.x + threadIdx.x;
    if (i < nOdd && ei32[2 * i + 1] != 0) *flag = 1;  // benign race
}

__global__ void normalize_kernel(const int* __restrict__ ei32, const int* __restrict__ b32,
                                 const int* __restrict__ flag,
                                 int* __restrict__ src, int* __restrict__ dst,
                                 int* __restrict__ batch32, int E, int N) {
    bool is64 = (*flag == 0);
    int i = blockIdx.x * blockDim.x + threadIdx.x;
    if (i < E) {
        if (is64) { src[i] = ei32[2 * i]; dst[i] = ei32[2 * (E + i)]; }
        else      { src[i] = ei32[i];     dst[i] = ei32[E + i]; }
    }
    if (i < N) batch32[i] = is64 ? b32[2 * i] : b32[i];
}

// ---------------- CSR build ----------------
__global__ void count_in_kernel(const int* __restrict__ dst, int* __restrict__ degi, int E) {
    int i = blockIdx.x * blockDim.x + threadIdx.x;
    if (i < E) atomicAdd(&degi[dst[i]], 1);
}

__global__ __launch_bounds__(256) void scan1_kernel(const int* __restrict__ degi,
                                                    int* __restrict__ rowptr,
                                                    int* __restrict__ bsums, int n) {
    __shared__ int s[256];
    int tid = threadIdx.x;
    int i = blockIdx.x * 256 + tid;
    int v = (i < n) ? degi[i] : 0;
    s[tid] = v; __syncthreads();
    for (int off = 1; off < 256; off <<= 1) {
        int t = (tid >= off) ? s[tid - off] : 0;
        __syncthreads(); s[tid] += t; __syncthreads();
    }
    if (i < n) rowptr[i] = s[tid] - v;
    if (tid == 255) bsums[blockIdx.x] = s[255];
}

__global__ __launch_bounds__(512) void scan2_kernel(int* __restrict__ bsums, int nb) {
    __shared__ int s[512];
    int tid = threadIdx.x;
    int v = (tid < nb) ? bsums[tid] : 0;
    s[tid] = v; __syncthreads();
    for (int off = 1; off < 512; off <<= 1) {
        int t = (tid >= off) ? s[tid - off] : 0;
        __syncthreads(); s[tid] += t; __syncthreads();
    }
    if (tid < nb) bsums[tid] = s[tid] - v;
}

__global__ void scan3_kernel(int* __restrict__ rowptr, const int* __restrict__ bsums,
                             int* __restrict__ cursor, const int* __restrict__ degi,
                             float* __restrict__ dinv, int n, int E) {
    int i = blockIdx.x * blockDim.x + threadIdx.x;
    if (i < n) {
        int r = rowptr[i] + bsums[i >> 8];
        rowptr[i] = r;
        cursor[i] = r;
        dinv[i] = 1.0f / sqrtf((float)(1 + degi[i]));
    }
    if (i == 0) rowptr[n] = E;
}

__global__ void fill_csr_kernel(const int* __restrict__ src, const int* __restrict__ dst,
                                int* __restrict__ cursor, int* __restrict__ csr, int E) {
    int e = blockIdx.x * blockDim.x + threadIdx.x;
    if (e < E) {
        int p = atomicAdd(&cursor[dst[e]], 1);
        csr[p] = src[e];
    }
}

// ---------------- fused conversions: x -> dinv-scaled bf16, W -> bf16 transposed ------
// x̃[i] = bf16(dinv[i] * x[i])   (aggregate-first: dinv[src] folded here)
__global__ void convert_kernel(const float* __restrict__ x, const float* __restrict__ dinv,
                               bf16_t* __restrict__ xb, int n4x,
                               const float* __restrict__ W1, const float* __restrict__ W2,
                               const float* __restrict__ W3, bf16_t* __restrict__ W1T,
                               bf16_t* __restrict__ W2T, bf16_t* __restrict__ W3T) {
    int idx = blockIdx.x * 256 + threadIdx.x;
    if (idx < n4x) {
        int row = idx >> 5;          // 32 float4 per 128-col row
        float di = dinv[row];
        float4 v = ((const float4*)x)[idx];
        ushort4 o;
        o.x = f2bf(v.x * di); o.y = f2bf(v.y * di);
        o.z = f2bf(v.z * di); o.w = f2bf(v.w * di);
        ((ushort4*)xb)[idx] = o;
        return;
    }
    int wj = idx - n4x;
    const int s1 = 128 * 256, s2 = s1 + 256 * 256, s3 = s2 + 256 * 256;
    if (wj < s1) {
        int k = wj >> 8, n = wj & 255;
        W1T[(size_t)n * 128 + k] = f2bf(W1[wj]);
    } else if (wj < s2) {
        int i2 = wj - s1; int k = i2 >> 8, n = i2 & 255;
        W2T[(size_t)n * 256 + k] = f2bf(W2[i2]);
    } else if (wj < s3) {
        int i3 = wj - s2; int k = i3 >> 8, n = i3 & 255;
        W3T[(size_t)n * 256 + k] = f2bf(W3[i3]);
    }
}

// ---------------- pre-gather (layer 1, 128 cols): Xa[i] = dinv[i]*(sum x̃[nb] + x̃[i]) ----
// quarter-wave (16 lanes) per 256B row; 4 rows per wave-iteration.
__global__ __launch_bounds__(256) void gather_pre_kernel(
    const bf16_t* __restrict__ xt, const int* __restrict__ rowptr,
    const int* __restrict__ csr, const float* __restrict__ dinv,
    bf16_t* __restrict__ xa, int M)
{
    int wave = threadIdx.x >> 6;
    int lane = threadIdx.x & 63;
    int i = blockIdx.x * 4 + wave;
    if (i >= M) return;
    int quarter = lane >> 4;
    int l4 = lane & 15;
    int c0 = l4 * 8;               // 8 bf16 = 16 B per lane; 16 lanes = 256 B row

    int b = rowptr[i];
    int cnt = 1 + (rowptr[i + 1] - b);
    float s[8] = {0.f, 0.f, 0.f, 0.f, 0.f, 0.f, 0.f, 0.f};

    int nq = (cnt + 3) >> 2;
    for (int t = 0; t < nq; ++t) {
        int ridx = 4 * t + quarter;
        if (ridx < cnt) {
            int row = (ridx == 0) ? i : csr[b + ridx - 1];
            ushort8_t v = *(const ushort8_t*)(xt + (size_t)row * 128 + c0);
            #pragma unroll
            for (int j = 0; j < 8; ++j) s[j] += bf2f(v[j]);
        }
    }
    #pragma unroll
    for (int j = 0; j < 8; ++j) {
        s[j] += __shfl_xor(s[j], 32, 64);
        s[j] += __shfl_xor(s[j], 16, 64);
    }
    if (quarter == 0) {
        float di = dinv[i];
        ushort8_t o;
        #pragma unroll
        for (int j = 0; j < 8; ++j) o[j] = f2bf(di * s[j]);
        *(ushort8_t*)(xa + (size_t)i * 128 + c0) = o;
    }
}

// ---------------- MFMA GEMM: BM=128, BN=256, BK=32, 512 thr, 2-phase dbuf ----------
// POST=true : out = acc*dinv[row]            (u, feeds post-gather)
// POST=false: out = relu(acc + bias[col])    (h, layer-1 aggregate-first)
// Double-buffered LDS (48 KB): STAGE(t+1) issued BEFORE compute(t); one barrier per
// K-step (catalog T3-minimum 2-phase; ~92% of 8-phase without T2/T5).
__device__ inline void gload_lds16(const bf16_t* g, bf16_t* l) {
    __builtin_amdgcn_global_load_lds(
        (const __attribute__((address_space(1))) unsigned int*)g,
        (__attribute__((address_space(3))) unsigned int*)l, 16, 0, 0);
}

template <bool POST>
__global__ __launch_bounds__(512, 6) void gemm_mfma_kernel(
    const bf16_t* __restrict__ A, const bf16_t* __restrict__ WT,  // WT: [256][K], K-contig
    const float* __restrict__ dinv, const float* __restrict__ bias,
    bf16_t* __restrict__ out, int M, int K)
{
    __shared__ bf16_t ldsA[2][128 * 32];   // 2 x 8 KB
    __shared__ bf16_t ldsB[2][256 * 32];   // 2 x 16 KB
    const int tid = threadIdx.x;
    const int wid = tid >> 6, lane = tid & 63;
    const int wr = wid >> 2, wc = wid & 3;         // 2x4 wave grid
    const int rowTile = blockIdx.x * 128;

    const int srow  = lane >> 2;          // 0..15 row within 16-row chunk
    const int skoff = (lane & 3) * 8;     // bf16 offset within 32-elem k-row

    f32x4 acc[4][4];
    #pragma unroll
    for (int m = 0; m < 4; ++m)
        #pragma unroll
        for (int n = 0; n < 4; ++n) acc[m][n] = (f32x4){0.f, 0.f, 0.f, 0.f};

    auto stage = [&](int buf, int k0) {
        #pragma unroll
        for (int c = 0; c < 3; ++c) {
            int q = wid * 3 + c;                       // 0..23
            if (q < 8) {
                int lrow = q * 16 + srow;              // 0..127
                int grow = rowTile + lrow; if (grow >= M) grow = M - 1;  // clamp; store guarded
                gload_lds16(A + (size_t)grow * K + k0 + skoff, &ldsA[buf][q * 512]);
            } else {
                int qb = q - 8;                        // 0..15
                int brow = qb * 16 + srow;             // 0..255
                gload_lds16(WT + (size_t)brow * K + k0 + skoff, &ldsB[buf][qb * 512]);
            }
        }
    };

    const int nt = K >> 5;
    stage(0, 0);
    __syncthreads();                       // drain prologue stage
    int cur = 0;
    for (int t = 0; t < nt; ++t) {
        if (t + 1 < nt) stage(cur ^ 1, (t + 1) << 5);   // prefetch next K-tile (overlaps compute)

        const int kr = (lane >> 4) * 8;
        const int fr = lane & 15;
        short8 a[4], b[4];
        #pragma unroll
        for (int m = 0; m < 4; ++m)
            a[m] = *(const short8*)(&ldsA[cur][(wr * 64 + m * 16 + fr) * 32 + kr]);
        #pragma unroll
        for (int n = 0; n < 4; ++n)
            b[n] = *(const short8*)(&ldsB[cur][(wc * 64 + n * 16 + fr) * 32 + kr]);
        #pragma unroll
        for (int m = 0; m < 4; ++m)
            #pragma unroll
            for (int n = 0; n < 4; ++n)
                acc[m][n] = __builtin_amdgcn_mfma_f32_16x16x32_bf16(a[m], b[n], acc[m][n], 0, 0, 0);

        if (t + 1 < nt) {                  // barrier drains prefetch (vmcnt0+lgkmcnt0) once per step
            __syncthreads();
            cur ^= 1;
        }
    }

    // epilogue: C/D layout col=lane&15, row=(lane>>4)*4+r (m89-verified)
    const int fr = lane & 15;
    #pragma unroll
    for (int m = 0; m < 4; ++m) {
        int rbase = rowTile + wr * 64 + m * 16 + ((lane >> 4) << 2);
        int ok[4];
        float di[4];
        #pragma unroll
        for (int r = 0; r < 4; ++r) {
            int g = rbase + r;
            ok[r] = (g < M);
            if (POST) di[r] = ok[r] ? dinv[g] : 0.f;
        }
        #pragma unroll
        for (int n = 0; n < 4; ++n) {
            int col = wc * 64 + n * 16 + fr;
            float bb = POST ? 0.f : bias[col];
            #pragma unroll
            for (int r = 0; r < 4; ++r) {
                if (!ok[r]) continue;
                float v = POST ? (acc[m][n][r] * di[r])
                               : fmaxf(acc[m][n][r] + bb, 0.f);
                out[(size_t)(rbase + r) * 256 + col] = f2bf(v);
            }
        }
    }
}

// ---------------- post-gather (256 cols): h[i] = relu(dinv[i]*(sum u[nb] + u[i]) + b) ----
__global__ __launch_bounds__(256) void gather_post_kernel(
    const bf16_t* __restrict__ u, const int* __restrict__ rowptr,
    const int* __restrict__ csr, const float* __restrict__ dinv,
    const float* __restrict__ bias, bf16_t* __restrict__ hout, int M)
{
    int wave = threadIdx.x >> 6;
    int lane = threadIdx.x & 63;
    int i = blockIdx.x * 4 + wave;
    if (i >= M) return;
    int half = lane >> 5;          // 0: even rows, 1: odd rows
    int l5   = lane & 31;
    int c0   = l5 * 8;             // 8 columns per lane (16 B)

    int b = rowptr[i];
    int cnt = 1 + (rowptr[i + 1] - b);   // self + neighbors
    float s[8] = {0.f, 0.f, 0.f, 0.f, 0.f, 0.f, 0.f, 0.f};

    int npairs = (cnt + 1) >> 1;
    for (int t = 0; t < npairs; ++t) {
        int ridx = 2 * t + half;
        if (ridx < cnt) {
            int row = (ridx == 0) ? i : csr[b + ridx - 1];
            ushort8_t v = *(const ushort8_t*)(u + (size_t)row * 256 + c0);
            #pragma unroll
            for (int j = 0; j < 8; ++j) s[j] += bf2f(v[j]);
        }
    }
    #pragma unroll
    for (int j = 0; j < 8; ++j) s[j] += __shfl_xor(s[j], 32, 64);

    if (half == 0) {
        float di = dinv[i];
        float4 bb0 = *(const float4*)(bias + c0);
        float4 bb1 = *(const float4*)(bias + c0 + 4);
        ushort8_t o;
        o[0] = f2bf(fmaxf(fmaf(di, s[0], bb0.x), 0.f));
        o[1] = f2bf(fmaxf(fmaf(di, s[1], bb0.y), 0.f));
        o[2] = f2bf(fmaxf(fmaf(di, s[2], bb0.z), 0.f));
        o[3] = f2bf(fmaxf(fmaf(di, s[3], bb0.w), 0.f));
        o[4] = f2bf(fmaxf(fmaf(di, s[4], bb1.x), 0.f));
        o[5] = f2bf(fmaxf(fmaf(di, s[5], bb1.y), 0.f));
        o[6] = f2bf(fmaxf(fmaf(di, s[6], bb1.z), 0.f));
        o[7] = f2bf(fmaxf(fmaf(di, s[7], bb1.w), 0.f));
        *(ushort8_t*)(hout + (size_t)i * 256 + c0) = o;
    }
}

// ---------------- pooling stage 1: (graph, slice) partial sums ----------------
__global__ __launch_bounds__(256) void pool1_kernel(
    const bf16_t* __restrict__ h, const int* __restrict__ batch,
    float* __restrict__ gpart, int M)
{
    int gi = blockIdx.x, slice = blockIdx.y;
    __shared__ int sS, sE;
    if (threadIdx.x == 0) {
        int lo = 0, hi = M;
        while (lo < hi) { int mid = (lo + hi) >> 1; if (batch[mid] < gi) lo = mid + 1; else hi = mid; }
        sS = lo;
        lo = 0; hi = M;
        while (lo < hi) { int mid = (lo + hi) >> 1; if (batch[mid] < gi + 1) lo = mid + 1; else hi = mid; }
        sE = lo;
    }
    __syncthreads();
    int start = sS, end = sE;
    int len = end - start;
    int chunk = (len + 3) >> 2;
    int rs = start + slice * chunk;
    int re = min(rs + chunk, end);

    int rg = threadIdx.x >> 5;
    int cb = threadIdx.x & 31;
    float a[8] = {0.f, 0.f, 0.f, 0.f, 0.f, 0.f, 0.f, 0.f};
    for (int r = rs + rg; r < re; r += 8) {
        ushort8_t v = *(const ushort8_t*)(h + (size_t)r * 256 + cb * 8);
        #pragma unroll
        for (int j = 0; j < 8; ++j) a[j] += bf2f(v[j]);
    }
    __shared__ float lds[8][256];
    #pragma unroll
    for (int j = 0; j < 8; ++j) lds[rg][cb * 8 + j] = a[j];
    __syncthreads();
    int t = threadIdx.x;
    float s = 0.f;
    #pragma unroll
    for (int g = 0; g < 8; ++g) s += lds[g][t];
    gpart[((size_t)slice * N_GRAPHS + gi) * 256 + t] = s;
}

// ---------------- pooling stage 2 ----------------
__global__ __launch_bounds__(256) void pool2_kernel(
    const float* __restrict__ gpart, const int* __restrict__ batch,
    float* __restrict__ gmean, int M)
{
    int gi = blockIdx.x;
    __shared__ int sS, sE;
    if (threadIdx.x == 0) {
        int lo = 0, hi = M;
        while (lo < hi) { int mid = (lo + hi) >> 1; if (batch[mid] < gi) lo = mid + 1; else hi = mid; }
        sS = lo;
        lo = 0; hi = M;
        while (lo < hi) { int mid = (lo + hi) >> 1; if (batch[mid] < gi + 1) lo = mid + 1; else hi = mid; }
        sE = lo;
    }
    __syncthreads();
    int t = threadIdx.x;
    float s = 0.f;
    #pragma unroll
    for (int sl = 0; sl < 4; ++sl) s += gpart[((size_t)sl * N_GRAPHS + gi) * 256 + t];
    gmean[(size_t)gi * 256 + t] = s / fmaxf((float)(sE - sS), 1.0f);
}

// ---------------- final FC ----------------
__global__ __launch_bounds__(128) void fc_kernel(
    const float* __restrict__ gmean, const float* __restrict__ Wfc,
    const float* __restrict__ bfc, float* __restrict__ out)
{
    int gi = blockIdx.x;
    int j = threadIdx.x;
    float s = bfc[j];
    const float* g = gmean + (size_t)gi * 256;
    for (int k = 0; k < 256; ++k) s = fmaf(g[k], Wfc[k * 128 + j], s);
    out[(size_t)gi * 128 + j] = s;
}

extern "C" void kernel_launch(void* const* d_in, const int* in_sizes, int n_in,
                              void* d_out, int out_size, void* d_ws, size_t ws_size,
                              hipStream_t stream) {
    const float* x    = (const float*)d_in[0];
    const int*   ei   = (const int*)d_in[1];
    const int*   bat  = (const int*)d_in[2];
    const float* W1   = (const float*)d_in[3];
    const float* b1   = (const float*)d_in[4];
    const float* W2   = (const float*)d_in[5];
    const float* b2   = (const float*)d_in[6];
    const float* W3   = (const float*)d_in[7];
    const float* b3   = (const float*)d_in[8];
    const float* Wfc  = (const float*)d_in[9];
    const float* bfc  = (const float*)d_in[10];

    const int N = N_NODES, E = N_EDGES;
    const size_t NB2 = (size_t)N * 256 * sizeof(bf16_t);  // 51.2 MB

    // ---- workspace carve (256B-aligned), total ≈ 113 MB ----
    char* p = (char*)d_ws;
    auto alloc = [&](size_t bytes) { char* r = p; p += (bytes + 255) & ~(size_t)255; return r; };
    bf16_t* u      = (bf16_t*)alloc(NB2);          // also holds Xa [N][128] for layer 1
    bf16_t* h      = (bf16_t*)alloc(NB2);          // also holds x̃ [N][128] before layer 1
    float*  dinv   = (float*)alloc((size_t)N * 4);
    float*  gmean  = (float*)alloc((size_t)N_GRAPHS * 256 * 4);
    float*  gpart  = (float*)alloc((size_t)4 * N_GRAPHS * 256 * 4);
    int*    src    = (int*)alloc((size_t)E * 4);
    int*    dst    = (int*)alloc((size_t)E * 4);
    int*    bat32  = (int*)alloc((size_t)N * 4);
    int*    degi   = (int*)alloc((size_t)N * 4);
    int*    rowptr = (int*)alloc((size_t)(N + 1) * 4);
    int*    cursor = (int*)alloc((size_t)N * 4);
    int*    csr    = (int*)alloc((size_t)E * 4);
    int*    bsums  = (int*)alloc(512 * 4);
    int*    flag   = (int*)alloc(4);
    bf16_t* W1T    = (bf16_t*)alloc((size_t)128 * 256 * 2);
    bf16_t* W2T    = (bf16_t*)alloc((size_t)256 * 256 * 2);
    bf16_t* W3T    = (bf16_t*)alloc((size_t)256 * 256 * 2);
    size_t needed = (size_t)(p - (char*)d_ws);
    if (ws_size < needed) {
        sentinel_kernel<<<(out_size + 255) / 256, 256, 0, stream>>>((float*)d_out, out_size);
        return;
    }

    const int nbScan = (N + 255) / 256;  // 391 <= 512
    const int n4x = N * 128 / 4;         // 3.2M float4s of x

    // ---- index normalize + CSR build + conversions (convert AFTER scan3: needs dinv) ----
    zero_misc_kernel<<<(N + 255) / 256, 256, 0, stream>>>(degi, flag, N);
    detect_kernel<<<(E + 255) / 256, 256, 0, stream>>>(ei, flag, E);
    normalize_kernel<<<(E + 255) / 256, 256, 0, stream>>>(ei, bat, flag, src, dst, bat32, E, N);
    count_in_kernel<<<(E + 255) / 256, 256, 0, stream>>>(dst, degi, E);
    scan1_kernel<<<nbScan, 256, 0, stream>>>(degi, rowptr, bsums, N);
    scan2_kernel<<<1, 512, 0, stream>>>(bsums, nbScan);
    scan3_kernel<<<(N + 255) / 256, 256, 0, stream>>>(rowptr, bsums, cursor, degi, dinv, N, E);
    fill_csr_kernel<<<(E + 255) / 256, 256, 0, stream>>>(src, dst, cursor, csr, E);
    convert_kernel<<<(n4x + 128 * 256 + 2 * 256 * 256 + 255) / 256, 256, 0, stream>>>(
        x, dinv, h, n4x, W1, W2, W3, W1T, W2T, W3T);

    int gemmBlocks = (N + 127) / 128;   // 782
    int gatherBlocks = (N + 3) / 4;

    // layer 1, aggregate-first: Xa = S·x̃ (128 cols), then h = relu(Xa·W1 + b1)
    gather_pre_kernel<<<gatherBlocks, 256, 0, stream>>>(h, rowptr, csr, dinv, u, N);
    gemm_mfma_kernel<false><<<gemmBlocks, 512, 0, stream>>>(u, W1T, dinv, b1, h, N, 128);
    // layer 2 (K=256): u = (h·W2)·dinv, h = relu(dinv·(S-sum u) + b2)
    gemm_mfma_kernel<true><<<gemmBlocks, 512, 0, stream>>>(h, W2T, dinv, b2, u, N, 256);
    gather_post_kernel<<<gatherBlocks, 256, 0, stream>>>(u, rowptr, csr, dinv, b2, h, N);
    // layer 3
    gemm_mfma_kernel<true><<<gemmBlocks, 512, 0, stream>>>(h, W3T, dinv, b3, u, N, 256);
    gather_post_kernel<<<gatherBlocks, 256, 0, stream>>>(u, rowptr, csr, dinv, b3, h, N);

    // pool (2-stage) + fc
    pool1_kernel<<<dim3(N_GRAPHS, 4), 256, 0, stream>>>(h, bat32, gpart, N);
    pool2_kernel<<<N_GRAPHS, 256, 0, stream>>>(gpart, bat32, gmean, N);
    fc_kernel<<<N_GRAPHS, 128, 0, stream>>>(gmean, Wfc, bfc, (float*)d_out);
}

// Round 10
// 425.011 us; speedup vs baseline: 1.6133x; 1.6133x over previous
//
#include <hip/hip_runtime.h>

#define N_NODES 100000
#define N_EDGES 320000
#define N_GRAPHS 512

typedef unsigned short bf16_t;
typedef __attribute__((ext_vector_type(8))) short short8;            // 8 bf16 = 4 VGPR
typedef __attribute__((ext_vector_type(8))) unsigned short ushort8_t;
typedef __attribute__((ext_vector_type(4))) float f32x4;

__device__ inline float bf2f(unsigned short b) {
    unsigned int u = ((unsigned int)b) << 16;
    float f; __builtin_memcpy(&f, &u, 4); return f;
}
__device__ inline unsigned short f2bf(float f) {
    unsigned int u; __builtin_memcpy(&u, &f, 4);
    u = (u + 0x7FFFu + ((u >> 16) & 1u)) >> 16;   // RNE
    return (unsigned short)u;
}

// ---------------- sentinel ----------------
__global__ void sentinel_kernel(float* out, int n) {
    int i = blockIdx.x * blockDim.x + threadIdx.x;
    if (i < n) out[i] = 12345.0f;
}

// ---------------- zero degi + flag ----------------
__global__ void zero_misc_kernel(int* __restrict__ degi, int* __restrict__ flag, int n) {
    int i = blockIdx.x * blockDim.x + threadIdx.x;
    if (i < n) degi[i] = 0;
    if (i == 0) *flag = 0;
}

// ---------------- int64-vs-int32 index detection ----------------
__global__ void detect_kernel(const int* __restrict__ ei32, int* __restrict__ flag, int nOdd) {
    int i = blockIdx.x * blockDim.x + threadIdx.x;
    if (i < nOdd && ei32[2 * i + 1] != 0) *flag = 1;  // benign race
}

__global__ void normalize_kernel(const int* __restrict__ ei32, const int* __restrict__ b32,
                                 const int* __restrict__ flag,
                                 int* __restrict__ src, int* __restrict__ dst,
                                 int* __restrict__ batch32, int E, int N) {
    bool is64 = (*flag == 0);
    int i = blockIdx.x * blockDim.x + threadIdx.x;
    if (i < E) {
        if (is64) { src[i] = ei32[2 * i]; dst[i] = ei32[2 * (E + i)]; }
        else      { src[i] = ei32[i];     dst[i] = ei32[E + i]; }
    }
    if (i < N) batch32[i] = is64 ? b32[2 * i] : b32[i];
}

// ---------------- CSR build ----------------
__global__ void count_in_kernel(const int* __restrict__ dst, int* __restrict__ degi, int E) {
    int i = blockIdx.x * blockDim.x + threadIdx.x;
    if (i < E) atomicAdd(&degi[dst[i]], 1);
}

__global__ __launch_bounds__(256) void scan1_kernel(const int* __restrict__ degi,
                                                    int* __restrict__ rowptr,
                                                    int* __restrict__ bsums, int n) {
    __shared__ int s[256];
    int tid = threadIdx.x;
    int i = blockIdx.x * 256 + tid;
    int v = (i < n) ? degi[i] : 0;
    s[tid] = v; __syncthreads();
    for (int off = 1; off < 256; off <<= 1) {
        int t = (tid >= off) ? s[tid - off] : 0;
        __syncthreads(); s[tid] += t; __syncthreads();
    }
    if (i < n) rowptr[i] = s[tid] - v;
    if (tid == 255) bsums[blockIdx.x] = s[255];
}

__global__ __launch_bounds__(512) void scan2_kernel(int* __restrict__ bsums, int nb) {
    __shared__ int s[512];
    int tid = threadIdx.x;
    int v = (tid < nb) ? bsums[tid] : 0;
    s[tid] = v; __syncthreads();
    for (int off = 1; off < 512; off <<= 1) {
        int t = (tid >= off) ? s[tid - off] : 0;
        __syncthreads(); s[tid] += t; __syncthreads();
    }
    if (tid < nb) bsums[tid] = s[tid] - v;
}

__global__ void scan3_kernel(int* __restrict__ rowptr, const int* __restrict__ bsums,
                             int* __restrict__ cursor, const int* __restrict__ degi,
                             float* __restrict__ dinv, int n, int E) {
    int i = blockIdx.x * blockDim.x + threadIdx.x;
    if (i < n) {
        int r = rowptr[i] + bsums[i >> 8];
        rowptr[i] = r;
        cursor[i] = r;
        dinv[i] = 1.0f / sqrtf((float)(1 + degi[i]));
    }
    if (i == 0) rowptr[n] = E;
}

__global__ void fill_csr_kernel(const int* __restrict__ src, const int* __restrict__ dst,
                                int* __restrict__ cursor, int* __restrict__ csr, int E) {
    int e = blockIdx.x * blockDim.x + threadIdx.x;
    if (e < E) {
        int p = atomicAdd(&cursor[dst[e]], 1);
        csr[p] = src[e];
    }
}

// ---------------- fused conversions: x -> dinv-scaled bf16, W -> bf16 transposed ------
// x̃[i] = bf16(dinv[i] * x[i])   (aggregate-first: dinv[src] folded here)
__global__ void convert_kernel(const float* __restrict__ x, const float* __restrict__ dinv,
                               bf16_t* __restrict__ xb, int n4x,
                               const float* __restrict__ W1, const float* __restrict__ W2,
                               const float* __restrict__ W3, bf16_t* __restrict__ W1T,
                               bf16_t* __restrict__ W2T, bf16_t* __restrict__ W3T) {
    int idx = blockIdx.x * 256 + threadIdx.x;
    if (idx < n4x) {
        int row = idx >> 5;          // 32 float4 per 128-col row
        float di = dinv[row];
        float4 v = ((const float4*)x)[idx];
        ushort4 o;
        o.x = f2bf(v.x * di); o.y = f2bf(v.y * di);
        o.z = f2bf(v.z * di); o.w = f2bf(v.w * di);
        ((ushort4*)xb)[idx] = o;
        return;
    }
    int wj = idx - n4x;
    const int s1 = 128 * 256, s2 = s1 + 256 * 256, s3 = s2 + 256 * 256;
    if (wj < s1) {
        int k = wj >> 8, n = wj & 255;
        W1T[(size_t)n * 128 + k] = f2bf(W1[wj]);
    } else if (wj < s2) {
        int i2 = wj - s1; int k = i2 >> 8, n = i2 & 255;
        W2T[(size_t)n * 256 + k] = f2bf(W2[i2]);
    } else if (wj < s3) {
        int i3 = wj - s2; int k = i3 >> 8, n = i3 & 255;
        W3T[(size_t)n * 256 + k] = f2bf(W3[i3]);
    }
}

// ---------------- pre-gather (layer 1, 128 cols): Xa[i] = dinv[i]*(sum x̃[nb] + x̃[i]) ----
// quarter-wave (16 lanes) per 256B row; 4 rows per wave-iteration.
__global__ __launch_bounds__(256) void gather_pre_kernel(
    const bf16_t* __restrict__ xt, const int* __restrict__ rowptr,
    const int* __restrict__ csr, const float* __restrict__ dinv,
    bf16_t* __restrict__ xa, int M)
{
    int wave = threadIdx.x >> 6;
    int lane = threadIdx.x & 63;
    int i = blockIdx.x * 4 + wave;
    if (i >= M) return;
    int quarter = lane >> 4;
    int l4 = lane & 15;
    int c0 = l4 * 8;               // 8 bf16 = 16 B per lane; 16 lanes = 256 B row

    int b = rowptr[i];
    int cnt = 1 + (rowptr[i + 1] - b);
    float s[8] = {0.f, 0.f, 0.f, 0.f, 0.f, 0.f, 0.f, 0.f};

    int nq = (cnt + 3) >> 2;
    for (int t = 0; t < nq; ++t) {
        int ridx = 4 * t + quarter;
        if (ridx < cnt) {
            int row = (ridx == 0) ? i : csr[b + ridx - 1];
            ushort8_t v = *(const ushort8_t*)(xt + (size_t)row * 128 + c0);
            #pragma unroll
            for (int j = 0; j < 8; ++j) s[j] += bf2f(v[j]);
        }
    }
    #pragma unroll
    for (int j = 0; j < 8; ++j) {
        s[j] += __shfl_xor(s[j], 32, 64);
        s[j] += __shfl_xor(s[j], 16, 64);
    }
    if (quarter == 0) {
        float di = dinv[i];
        ushort8_t o;
        #pragma unroll
        for (int j = 0; j < 8; ++j) o[j] = f2bf(di * s[j]);
        *(ushort8_t*)(xa + (size_t)i * 128 + c0) = o;
    }
}

// ---------------- MFMA GEMM: BM=128, BN=256, BK=32, 512 thr, 2-phase dbuf ----------
// POST=true : out = acc*dinv[row]            (u, feeds post-gather)
// POST=false: out = relu(acc + bias[col])    (h, layer-1 aggregate-first)
// Double-buffered LDS (48 KB): STAGE(t+1) issued BEFORE compute(t); one barrier per
// K-step. NO min-waves launch-bounds cap: R8 showed (512,6) capped VGPR to 40 and
// spilled the 64-VGPR accumulator to scratch (WRITE_SIZE 358 MB, 145 us).
__device__ inline void gload_lds16(const bf16_t* g, bf16_t* l) {
    __builtin_amdgcn_global_load_lds(
        (const __attribute__((address_space(1))) unsigned int*)g,
        (__attribute__((address_space(3))) unsigned int*)l, 16, 0, 0);
}

template <bool POST>
__global__ __launch_bounds__(512) void gemm_mfma_kernel(
    const bf16_t* __restrict__ A, const bf16_t* __restrict__ WT,  // WT: [256][K], K-contig
    const float* __restrict__ dinv, const float* __restrict__ bias,
    bf16_t* __restrict__ out, int M, int K)
{
    __shared__ bf16_t ldsA[2][128 * 32];   // 2 x 8 KB
    __shared__ bf16_t ldsB[2][256 * 32];   // 2 x 16 KB
    const int tid = threadIdx.x;
    const int wid = tid >> 6, lane = tid & 63;
    const int wr = wid >> 2, wc = wid & 3;         // 2x4 wave grid
    const int rowTile = blockIdx.x * 128;

    const int srow  = lane >> 2;          // 0..15 row within 16-row chunk
    const int skoff = (lane & 3) * 8;     // bf16 offset within 32-elem k-row

    f32x4 acc[4][4];
    #pragma unroll
    for (int m = 0; m < 4; ++m)
        #pragma unroll
        for (int n = 0; n < 4; ++n) acc[m][n] = (f32x4){0.f, 0.f, 0.f, 0.f};

    auto stage = [&](int buf, int k0) {
        #pragma unroll
        for (int c = 0; c < 3; ++c) {
            int q = wid * 3 + c;                       // 0..23
            if (q < 8) {
                int lrow = q * 16 + srow;              // 0..127
                int grow = rowTile + lrow; if (grow >= M) grow = M - 1;  // clamp; store guarded
                gload_lds16(A + (size_t)grow * K + k0 + skoff, &ldsA[buf][q * 512]);
            } else {
                int qb = q - 8;                        // 0..15
                int brow = qb * 16 + srow;             // 0..255
                gload_lds16(WT + (size_t)brow * K + k0 + skoff, &ldsB[buf][qb * 512]);
            }
        }
    };

    const int nt = K >> 5;
    stage(0, 0);
    __syncthreads();                       // drain prologue stage
    int cur = 0;
    for (int t = 0; t < nt; ++t) {
        if (t + 1 < nt) stage(cur ^ 1, (t + 1) << 5);   // prefetch next K-tile (overlaps compute)

        const int kr = (lane >> 4) * 8;
        const int fr = lane & 15;
        short8 a[4], b[4];
        #pragma unroll
        for (int m = 0; m < 4; ++m)
            a[m] = *(const short8*)(&ldsA[cur][(wr * 64 + m * 16 + fr) * 32 + kr]);
        #pragma unroll
        for (int n = 0; n < 4; ++n)
            b[n] = *(const short8*)(&ldsB[cur][(wc * 64 + n * 16 + fr) * 32 + kr]);
        #pragma unroll
        for (int m = 0; m < 4; ++m)
            #pragma unroll
            for (int n = 0; n < 4; ++n)
                acc[m][n] = __builtin_amdgcn_mfma_f32_16x16x32_bf16(a[m], b[n], acc[m][n], 0, 0, 0);

        if (t + 1 < nt) {                  // barrier drains prefetch once per step
            __syncthreads();
            cur ^= 1;
        }
    }

    // epilogue: C/D layout col=lane&15, row=(lane>>4)*4+r (m89-verified)
    const int fr = lane & 15;
    #pragma unroll
    for (int m = 0; m < 4; ++m) {
        int rbase = rowTile + wr * 64 + m * 16 + ((lane >> 4) << 2);
        int ok[4];
        float di[4];
        #pragma unroll
        for (int r = 0; r < 4; ++r) {
            int g = rbase + r;
            ok[r] = (g < M);
            if (POST) di[r] = ok[r] ? dinv[g] : 0.f;
        }
        #pragma unroll
        for (int n = 0; n < 4; ++n) {
            int col = wc * 64 + n * 16 + fr;
            float bb = POST ? 0.f : bias[col];
            #pragma unroll
            for (int r = 0; r < 4; ++r) {
                if (!ok[r]) continue;
                float v = POST ? (acc[m][n][r] * di[r])
                               : fmaxf(acc[m][n][r] + bb, 0.f);
                out[(size_t)(rbase + r) * 256 + col] = f2bf(v);
            }
        }
    }
}

// ---------------- post-gather (256 cols): h[i] = relu(dinv[i]*(sum u[nb] + u[i]) + b) ----
__global__ __launch_bounds__(256) void gather_post_kernel(
    const bf16_t* __restrict__ u, const int* __restrict__ rowptr,
    const int* __restrict__ csr, const float* __restrict__ dinv,
    const float* __restrict__ bias, bf16_t* __restrict__ hout, int M)
{
    int wave = threadIdx.x >> 6;
    int lane = threadIdx.x & 63;
    int i = blockIdx.x * 4 + wave;
    if (i >= M) return;
    int half = lane >> 5;          // 0: even rows, 1: odd rows
    int l5   = lane & 31;
    int c0   = l5 * 8;             // 8 columns per lane (16 B)

    int b = rowptr[i];
    int cnt = 1 + (rowptr[i + 1] - b);   // self + neighbors
    float s[8] = {0.f, 0.f, 0.f, 0.f, 0.f, 0.f, 0.f, 0.f};

    int npairs = (cnt + 1) >> 1;
    for (int t = 0; t < npairs; ++t) {
        int ridx = 2 * t + half;
        if (ridx < cnt) {
            int row = (ridx == 0) ? i : csr[b + ridx - 1];
            ushort8_t v = *(const ushort8_t*)(u + (size_t)row * 256 + c0);
            #pragma unroll
            for (int j = 0; j < 8; ++j) s[j] += bf2f(v[j]);
        }
    }
    #pragma unroll
    for (int j = 0; j < 8; ++j) s[j] += __shfl_xor(s[j], 32, 64);

    if (half == 0) {
        float di = dinv[i];
        float4 bb0 = *(const float4*)(bias + c0);
        float4 bb1 = *(const float4*)(bias + c0 + 4);
        ushort8_t o;
        o[0] = f2bf(fmaxf(fmaf(di, s[0], bb0.x), 0.f));
        o[1] = f2bf(fmaxf(fmaf(di, s[1], bb0.y), 0.f));
        o[2] = f2bf(fmaxf(fmaf(di, s[2], bb0.z), 0.f));
        o[3] = f2bf(fmaxf(fmaf(di, s[3], bb0.w), 0.f));
        o[4] = f2bf(fmaxf(fmaf(di, s[4], bb1.x), 0.f));
        o[5] = f2bf(fmaxf(fmaf(di, s[5], bb1.y), 0.f));
        o[6] = f2bf(fmaxf(fmaf(di, s[6], bb1.z), 0.f));
        o[7] = f2bf(fmaxf(fmaf(di, s[7], bb1.w), 0.f));
        *(ushort8_t*)(hout + (size_t)i * 256 + c0) = o;
    }
}

// ---------------- pooling stage 1: (graph, slice) partial sums ----------------
__global__ __launch_bounds__(256) void pool1_kernel(
    const bf16_t* __restrict__ h, const int* __restrict__ batch,
    float* __restrict__ gpart, int M)
{
    int gi = blockIdx.x, slice = blockIdx.y;
    __shared__ int sS, sE;
    if (threadIdx.x == 0) {
        int lo = 0, hi = M;
        while (lo < hi) { int mid = (lo + hi) >> 1; if (batch[mid] < gi) lo = mid + 1; else hi = mid; }
        sS = lo;
        lo = 0; hi = M;
        while (lo < hi) { int mid = (lo + hi) >> 1; if (batch[mid] < gi + 1) lo = mid + 1; else hi = mid; }
        sE = lo;
    }
    __syncthreads();
    int start = sS, end = sE;
    int len = end - start;
    int chunk = (len + 3) >> 2;
    int rs = start + slice * chunk;
    int re = min(rs + chunk, end);

    int rg = threadIdx.x >> 5;
    int cb = threadIdx.x & 31;
    float a[8] = {0.f, 0.f, 0.f, 0.f, 0.f, 0.f, 0.f, 0.f};
    for (int r = rs + rg; r < re; r += 8) {
        ushort8_t v = *(const ushort8_t*)(h + (size_t)r * 256 + cb * 8);
        #pragma unroll
        for (int j = 0; j < 8; ++j) a[j] += bf2f(v[j]);
    }
    __shared__ float lds[8][256];
    #pragma unroll
    for (int j = 0; j < 8; ++j) lds[rg][cb * 8 + j] = a[j];
    __syncthreads();
    int t = threadIdx.x;
    float s = 0.f;
    #pragma unroll
    for (int g = 0; g < 8; ++g) s += lds[g][t];
    gpart[((size_t)slice * N_GRAPHS + gi) * 256 + t] = s;
}

// ---------------- pooling stage 2 ----------------
__global__ __launch_bounds__(256) void pool2_kernel(
    const float* __restrict__ gpart, const int* __restrict__ batch,
    float* __restrict__ gmean, int M)
{
    int gi = blockIdx.x;
    __shared__ int sS, sE;
    if (threadIdx.x == 0) {
        int lo = 0, hi = M;
        while (lo < hi) { int mid = (lo + hi) >> 1; if (batch[mid] < gi) lo = mid + 1; else hi = mid; }
        sS = lo;
        lo = 0; hi = M;
        while (lo < hi) { int mid = (lo + hi) >> 1; if (batch[mid] < gi + 1) lo = mid + 1; else hi = mid; }
        sE = lo;
    }
    __syncthreads();
    int t = threadIdx.x;
    float s = 0.f;
    #pragma unroll
    for (int sl = 0; sl < 4; ++sl) s += gpart[((size_t)sl * N_GRAPHS + gi) * 256 + t];
    gmean[(size_t)gi * 256 + t] = s / fmaxf((float)(sE - sS), 1.0f);
}

// ---------------- final FC ----------------
__global__ __launch_bounds__(128) void fc_kernel(
    const float* __restrict__ gmean, const float* __restrict__ Wfc,
    const float* __restrict__ bfc, float* __restrict__ out)
{
    int gi = blockIdx.x;
    int j = threadIdx.x;
    float s = bfc[j];
    const float* g = gmean + (size_t)gi * 256;
    for (int k = 0; k < 256; ++k) s = fmaf(g[k], Wfc[k * 128 + j], s);
    out[(size_t)gi * 128 + j] = s;
}

extern "C" void kernel_launch(void* const* d_in, const int* in_sizes, int n_in,
                              void* d_out, int out_size, void* d_ws, size_t ws_size,
                              hipStream_t stream) {
    const float* x    = (const float*)d_in[0];
    const int*   ei   = (const int*)d_in[1];
    const int*   bat  = (const int*)d_in[2];
    const float* W1   = (const float*)d_in[3];
    const float* b1   = (const float*)d_in[4];
    const float* W2   = (const float*)d_in[5];
    const float* b2   = (const float*)d_in[6];
    const float* W3   = (const float*)d_in[7];
    const float* b3   = (const float*)d_in[8];
    const float* Wfc  = (const float*)d_in[9];
    const float* bfc  = (const float*)d_in[10];

    const int N = N_NODES, E = N_EDGES;
    const size_t NB2 = (size_t)N * 256 * sizeof(bf16_t);  // 51.2 MB

    // ---- workspace carve (256B-aligned), total ≈ 113 MB ----
    char* p = (char*)d_ws;
    auto alloc = [&](size_t bytes) { char* r = p; p += (bytes + 255) & ~(size_t)255; return r; };
    bf16_t* u      = (bf16_t*)alloc(NB2);          // also holds Xa [N][128] for layer 1
    bf16_t* h      = (bf16_t*)alloc(NB2);          // also holds x̃ [N][128] before layer 1
    float*  dinv   = (float*)alloc((size_t)N * 4);
    float*  gmean  = (float*)alloc((size_t)N_GRAPHS * 256 * 4);
    float*  gpart  = (float*)alloc((size_t)4 * N_GRAPHS * 256 * 4);
    int*    src    = (int*)alloc((size_t)E * 4);
    int*    dst    = (int*)alloc((size_t)E * 4);
    int*    bat32  = (int*)alloc((size_t)N * 4);
    int*    degi   = (int*)alloc((size_t)N * 4);
    int*    rowptr = (int*)alloc((size_t)(N + 1) * 4);
    int*    cursor = (int*)alloc((size_t)N * 4);
    int*    csr    = (int*)alloc((size_t)E * 4);
    int*    bsums  = (int*)alloc(512 * 4);
    int*    flag   = (int*)alloc(4);
    bf16_t* W1T    = (bf16_t*)alloc((size_t)128 * 256 * 2);
    bf16_t* W2T    = (bf16_t*)alloc((size_t)256 * 256 * 2);
    bf16_t* W3T    = (bf16_t*)alloc((size_t)256 * 256 * 2);
    size_t needed = (size_t)(p - (char*)d_ws);
    if (ws_size < needed) {
        sentinel_kernel<<<(out_size + 255) / 256, 256, 0, stream>>>((float*)d_out, out_size);
        return;
    }

    const int nbScan = (N + 255) / 256;  // 391 <= 512
    const int n4x = N * 128 / 4;         // 3.2M float4s of x

    // ---- index normalize + CSR build + conversions (convert AFTER scan3: needs dinv) ----
    zero_misc_kernel<<<(N + 255) / 256, 256, 0, stream>>>(degi, flag, N);
    detect_kernel<<<(E + 255) / 256, 256, 0, stream>>>(ei, flag, E);
    normalize_kernel<<<(E + 255) / 256, 256, 0, stream>>>(ei, bat, flag, src, dst, bat32, E, N);
    count_in_kernel<<<(E + 255) / 256, 256, 0, stream>>>(dst, degi, E);
    scan1_kernel<<<nbScan, 256, 0, stream>>>(degi, rowptr, bsums, N);
    scan2_kernel<<<1, 512, 0, stream>>>(bsums, nbScan);
    scan3_kernel<<<(N + 255) / 256, 256, 0, stream>>>(rowptr, bsums, cursor, degi, dinv, N, E);
    fill_csr_kernel<<<(E + 255) / 256, 256, 0, stream>>>(src, dst, cursor, csr, E);
    convert_kernel<<<(n4x + 128 * 256 + 2 * 256 * 256 + 255) / 256, 256, 0, stream>>>(
        x, dinv, h, n4x, W1, W2, W3, W1T, W2T, W3T);

    int gemmBlocks = (N + 127) / 128;   // 782
    int gatherBlocks = (N + 3) / 4;

    // layer 1, aggregate-first: Xa = S·x̃ (128 cols), then h = relu(Xa·W1 + b1)
    gather_pre_kernel<<<gatherBlocks, 256, 0, stream>>>(h, rowptr, csr, dinv, u, N);
    gemm_mfma_kernel<false><<<gemmBlocks, 512, 0, stream>>>(u, W1T, dinv, b1, h, N, 128);
    // layer 2 (K=256): u = (h·W2)·dinv, h = relu(dinv·(S-sum u) + b2)
    gemm_mfma_kernel<true><<<gemmBlocks, 512, 0, stream>>>(h, W2T, dinv, b2, u, N, 256);
    gather_post_kernel<<<gatherBlocks, 256, 0, stream>>>(u, rowptr, csr, dinv, b2, h, N);
    // layer 3
    gemm_mfma_kernel<true><<<gemmBlocks, 512, 0, stream>>>(h, W3T, dinv, b3, u, N, 256);
    gather_post_kernel<<<gatherBlocks, 256, 0, stream>>>(u, rowptr, csr, dinv, b3, h, N);

    // pool (2-stage) + fc
    pool1_kernel<<<dim3(N_GRAPHS, 4), 256, 0, stream>>>(h, bat32, gpart, N);
    pool2_kernel<<<N_GRAPHS, 256, 0, stream>>>(gpart, bat32, gmean, N);
    fc_kernel<<<N_GRAPHS, 128, 0, stream>>>(gmean, Wfc, bfc, (float*)d_out);
}